// Round 1
// baseline (55.350 us; speedup 1.0000x reference)
//
#include <hip/hip_runtime.h>

#define NB 32
#define NC 256
#define HW 4096   // 64*64
#define RDIM 16   // C/R = 256/16
#define KTOP 128

// ---------------------------------------------------------------------------
// Kernel 1: global average pool. One block per (b,c) plane of 4096 floats.
// ---------------------------------------------------------------------------
__global__ __launch_bounds__(256) void pool_kernel(const float* __restrict__ x,
                                                   float* __restrict__ y) {
    const int plane = blockIdx.x;                       // 0 .. NB*NC-1
    const float4* __restrict__ xin =
        reinterpret_cast<const float4*>(x + (size_t)plane * HW);
    const int t = threadIdx.x;                          // 0..255
    float s = 0.f;
#pragma unroll
    for (int i = 0; i < 4; ++i) {                       // 1024 float4 / 256 thr
        float4 v = xin[t + i * 256];
        s += (v.x + v.y) + (v.z + v.w);
    }
    // wave-64 reduction
#pragma unroll
    for (int off = 32; off > 0; off >>= 1) s += __shfl_down(s, off);
    __shared__ float ws[4];
    const int wid = t >> 6, lane = t & 63;
    if (lane == 0) ws[wid] = s;
    __syncthreads();
    if (t == 0) {
        float tot = (ws[0] + ws[1]) + (ws[2] + ws[3]);
        y[plane] = tot * (1.0f / HW);
    }
}

// ---------------------------------------------------------------------------
// Kernel 2: squeeze-excite MLP + sigmoid + top-k(128) with ascending index
// order. One block (256 threads) per batch element.
// ---------------------------------------------------------------------------
__global__ __launch_bounds__(256) void se_topk_kernel(
    const float* __restrict__ y,
    const float* __restrict__ w1, const float* __restrict__ b1,
    const float* __restrict__ w2, const float* __restrict__ b2,
    int* __restrict__ idx_out, float* __restrict__ aw_out) {
    const int b = blockIdx.x;
    const int t = threadIdx.x;                          // == channel index
    __shared__ float ych[NC];
    __shared__ float hsh[RDIM];
    __shared__ float attn[NC];
    __shared__ int   sel[NC];

    ych[t] = y[b * NC + t];
    __syncthreads();

    // h[r] = relu(sum_c y[c]*w1[r,c] + b1[r]); 16 groups of 16 lanes.
    const int r = t >> 4;                               // 0..15
    const int j = t & 15;                               // 0..15
    float partial = 0.f;
#pragma unroll
    for (int k = 0; k < 16; ++k) {
        const int c = j * 16 + k;
        partial += ych[c] * w1[r * NC + c];
    }
#pragma unroll
    for (int m = 8; m > 0; m >>= 1) partial += __shfl_xor(partial, m, 16);
    if (j == 0) hsh[r] = fmaxf(partial + b1[r], 0.f);
    __syncthreads();

    // attn[c] = sigmoid(sum_r h[r]*w2[c,r] + b2[c]); one thread per channel.
    float z = b2[t];
#pragma unroll
    for (int rr = 0; rr < RDIM; ++rr) z += hsh[rr] * w2[t * RDIM + rr];
    const float v = 1.0f / (1.0f + __expf(-z));
    attn[t] = v;
    __syncthreads();

    // rank of this channel (strict order, tie -> lower index wins, matching
    // jax.lax.top_k tie-breaking).
    int rank = 0;
    for (int c = 0; c < NC; ++c) {
        const float o = attn[c];
        rank += (o > v) || (o == v && c < t);
    }
    const int s = (rank < KTOP) ? 1 : 0;
    sel[t] = s;
    __syncthreads();

    if (s) {
        // output slot = number of selected channels with smaller index
        // (selected indices sorted ascending).
        int pos = 0;
        for (int c = 0; c < t; ++c) pos += sel[c];
        idx_out[b * KTOP + pos] = t;
        aw_out[b * KTOP + pos] = v;
    }
}

// ---------------------------------------------------------------------------
// Kernel 3: gather selected channels of x, scale by attention weight, write.
// One block per (b,k) output plane.
// ---------------------------------------------------------------------------
__global__ __launch_bounds__(256) void gather_scale_kernel(
    const float* __restrict__ x,
    const int* __restrict__ idx, const float* __restrict__ aw,
    float* __restrict__ out) {
    const int p = blockIdx.x;                           // 0 .. NB*KTOP-1
    const int b = p >> 7;                               // /128
    const int c = idx[p];
    const float w = aw[p];
    const float4* __restrict__ xin =
        reinterpret_cast<const float4*>(x + ((size_t)(b * NC + c)) * HW);
    float4* __restrict__ o = reinterpret_cast<float4*>(out + (size_t)p * HW);
    const int t = threadIdx.x;
#pragma unroll
    for (int i = 0; i < 4; ++i) {
        float4 vv = xin[t + i * 256];
        o[t + i * 256] = make_float4(w * vv.x, w * vv.y, w * vv.z, w * vv.w);
    }
}

// ---------------------------------------------------------------------------
extern "C" void kernel_launch(void* const* d_in, const int* in_sizes, int n_in,
                              void* d_out, int out_size, void* d_ws, size_t ws_size,
                              hipStream_t stream) {
    const float* x  = (const float*)d_in[0];
    const float* w1 = (const float*)d_in[1];
    const float* b1 = (const float*)d_in[2];
    const float* w2 = (const float*)d_in[3];
    const float* b2 = (const float*)d_in[4];
    float* out = (float*)d_out;

    // workspace layout: y[NB*NC] f32 | idx[NB*KTOP] i32 | aw[NB*KTOP] f32
    float* y   = (float*)d_ws;
    int*   idx = (int*)(y + NB * NC);
    float* aw  = (float*)(idx + NB * KTOP);

    pool_kernel<<<NB * NC, 256, 0, stream>>>(x, y);
    se_topk_kernel<<<NB, 256, 0, stream>>>(y, w1, b1, w2, b2, idx, aw);
    gather_scale_kernel<<<NB * KTOP, 256, 0, stream>>>(x, idx, aw, out);
}

// Round 2
// 55.104 us; speedup vs baseline: 1.0045x; 1.0045x over previous
//
#include <hip/hip_runtime.h>

#define NB 32
#define NC 256
#define HW 4096   // 64*64
#define RDIM 16   // C/R = 256/16
#define KTOP 128

typedef float v4f __attribute__((ext_vector_type(4)));

// ---------------------------------------------------------------------------
// Kernel 1: global average pool. One WAVE per (b,c) plane (4 planes/block).
// 16 independent float4 loads per lane, pure shfl reduction, no LDS.
// ---------------------------------------------------------------------------
__global__ __launch_bounds__(256) void pool_kernel(const float* __restrict__ x,
                                                   float* __restrict__ y) {
    const int wid  = threadIdx.x >> 6;
    const int lane = threadIdx.x & 63;
    const int plane = blockIdx.x * 4 + wid;             // 0 .. NB*NC-1
    const v4f* __restrict__ xin = (const v4f*)(x + (size_t)plane * HW);
    float s = 0.f;
#pragma unroll
    for (int i = 0; i < 16; ++i) {                      // 1024 v4 / 64 lanes
        v4f v = xin[lane + i * 64];
        s += (v.x + v.y) + (v.z + v.w);
    }
#pragma unroll
    for (int off = 32; off > 0; off >>= 1) s += __shfl_down(s, off);
    if (lane == 0) y[plane] = s * (1.0f / HW);
}

// ---------------------------------------------------------------------------
// Kernel 2: SE-MLP + sigmoid + top-k(128), ascending index order.
// One block (256 threads) per batch element. Ballot-based compaction.
// ---------------------------------------------------------------------------
__global__ __launch_bounds__(256) void se_topk_kernel(
    const float* __restrict__ y,
    const float* __restrict__ w1, const float* __restrict__ b1,
    const float* __restrict__ w2, const float* __restrict__ b2,
    int* __restrict__ idx_out, float* __restrict__ aw_out) {
    const int b = blockIdx.x;
    const int t = threadIdx.x;                          // == channel index
    const int wid = t >> 6, lane = t & 63;
    __shared__ float ych[NC];
    __shared__ float hsh[RDIM];
    __shared__ float attn[NC];
    __shared__ unsigned long long masks[4];

    ych[t] = y[b * NC + t];
    __syncthreads();

    // h[r] = relu(sum_c y[c]*w1[r,c] + b1[r]); 16 groups of 16 lanes.
    const int r = t >> 4;                               // 0..15
    const int j = t & 15;                               // 0..15
    float partial = 0.f;
#pragma unroll
    for (int k = 0; k < 16; ++k) {
        const int c = j * 16 + k;
        partial += ych[c] * w1[r * NC + c];
    }
#pragma unroll
    for (int m = 8; m > 0; m >>= 1) partial += __shfl_xor(partial, m, 16);
    if (j == 0) hsh[r] = fmaxf(partial + b1[r], 0.f);
    __syncthreads();

    // attn[c] = sigmoid(sum_r h[r]*w2[c,r] + b2[c]); one thread per channel.
    float z = b2[t];
#pragma unroll
    for (int rr = 0; rr < RDIM; ++rr) z += hsh[rr] * w2[t * RDIM + rr];
    const float v = 1.0f / (1.0f + __expf(-z));
    attn[t] = v;
    __syncthreads();

    // rank (strict order, tie -> lower index wins == jax.lax.top_k).
    int rank = 0;
#pragma unroll 4
    for (int c = 0; c < NC; ++c) {
        const float o = attn[c];
        rank += (o > v) || (o == v && c < t);
    }
    const bool s = (rank < KTOP);

    // ballot-based compaction: pos = # selected with smaller channel index.
    const unsigned long long m = __ballot(s);
    if (lane == 0) masks[wid] = m;
    __syncthreads();
    if (s) {
        int pos = __popcll(m & ((lane == 63) ? 0x7FFFFFFFFFFFFFFFull
                                             : ((1ull << lane) - 1ull)));
        for (int w = 0; w < 4; ++w) pos += (w < wid) ? __popcll(masks[w]) : 0;
        idx_out[b * KTOP + pos] = t;
        aw_out[b * KTOP + pos] = v;
    }
}

// ---------------------------------------------------------------------------
// Kernel 3: gather selected channels of x, scale, non-temporal store.
// One WAVE per (b,k) output plane (4 planes/block).
// ---------------------------------------------------------------------------
__global__ __launch_bounds__(256) void gather_scale_kernel(
    const float* __restrict__ x,
    const int* __restrict__ idx, const float* __restrict__ aw,
    float* __restrict__ out) {
    const int wid  = threadIdx.x >> 6;
    const int lane = threadIdx.x & 63;
    const int p = blockIdx.x * 4 + wid;                 // 0 .. NB*KTOP-1
    const int b = p >> 7;                               // /128
    const int c = idx[p];
    const float w = aw[p];
    const v4f* __restrict__ xin =
        (const v4f*)(x + ((size_t)b * NC + c) * HW);
    v4f* __restrict__ o = (v4f*)(out + (size_t)p * HW);
#pragma unroll
    for (int i = 0; i < 16; ++i) {
        v4f v = xin[lane + i * 64];
        v4f rr = v * w;
        __builtin_nontemporal_store(rr, &o[lane + i * 64]);
    }
}

// ---------------------------------------------------------------------------
extern "C" void kernel_launch(void* const* d_in, const int* in_sizes, int n_in,
                              void* d_out, int out_size, void* d_ws, size_t ws_size,
                              hipStream_t stream) {
    const float* x  = (const float*)d_in[0];
    const float* w1 = (const float*)d_in[1];
    const float* b1 = (const float*)d_in[2];
    const float* w2 = (const float*)d_in[3];
    const float* b2 = (const float*)d_in[4];
    float* out = (float*)d_out;

    // workspace layout: y[NB*NC] f32 | idx[NB*KTOP] i32 | aw[NB*KTOP] f32
    float* y   = (float*)d_ws;
    int*   idx = (int*)(y + NB * NC);
    float* aw  = (float*)(idx + NB * KTOP);

    pool_kernel<<<NB * NC / 4, 256, 0, stream>>>(x, y);
    se_topk_kernel<<<NB, 256, 0, stream>>>(y, w1, b1, w2, b2, idx, aw);
    gather_scale_kernel<<<NB * KTOP / 4, 256, 0, stream>>>(x, idx, aw, out);
}

// Round 3
// 53.792 us; speedup vs baseline: 1.0290x; 1.0244x over previous
//
#include <hip/hip_runtime.h>

#define NB 32
#define NC 256
#define HW 4096   // 64*64
#define RDIM 16   // C/R = 256/16
#define KTOP 128

typedef float v4f __attribute__((ext_vector_type(4)));

// ---------------------------------------------------------------------------
// Kernel 1: global average pool. One WAVE per (b,c) plane (4 planes/block).
// ---------------------------------------------------------------------------
__global__ __launch_bounds__(256) void pool_kernel(const float* __restrict__ x,
                                                   float* __restrict__ y) {
    const int wid  = threadIdx.x >> 6;
    const int lane = threadIdx.x & 63;
    const int plane = blockIdx.x * 4 + wid;             // 0 .. NB*NC-1
    const v4f* __restrict__ xin = (const v4f*)(x + (size_t)plane * HW);
    float s = 0.f;
#pragma unroll
    for (int i = 0; i < 16; ++i) {                      // 1024 v4 / 64 lanes
        v4f v = xin[lane + i * 64];
        s += (v.x + v.y) + (v.z + v.w);
    }
#pragma unroll
    for (int off = 32; off > 0; off >>= 1) s += __shfl_down(s, off);
    if (lane == 0) y[plane] = s * (1.0f / HW);
}

// ---------------------------------------------------------------------------
// Kernel 2 (fused): SE-MLP + sigmoid + top-k(128) recomputed per block in
// LDS, then gather+scale of this block's 4 output planes. 1024 blocks,
// 32 blocks per batch element; the redundant MLP/top-k is ~0.3 us and fully
// parallel, removing the 32-block latency-bound kernel + one graph edge.
// ---------------------------------------------------------------------------
__global__ __launch_bounds__(256) void se_topk_gather_kernel(
    const float* __restrict__ x, const float* __restrict__ y,
    const float* __restrict__ w1, const float* __restrict__ b1,
    const float* __restrict__ w2, const float* __restrict__ b2,
    float* __restrict__ out) {
    const int blk = blockIdx.x;                         // 0..1023
    const int b   = blk >> 5;                           // 32 blocks / batch
    const int t   = threadIdx.x;                        // == channel index
    const int wid = t >> 6, lane = t & 63;

    __shared__ float ych[NC];
    __shared__ float hsh[RDIM];
    __shared__ float attn[NC];
    __shared__ unsigned long long masks[4];
    __shared__ int   sidx[KTOP];
    __shared__ float saw[KTOP];

    ych[t] = y[b * NC + t];
    __syncthreads();

    // h[r] = relu(sum_c y[c]*w1[r,c] + b1[r]); 16 groups of 16 lanes.
    const int r = t >> 4;
    const int j = t & 15;
    float partial = 0.f;
#pragma unroll
    for (int k = 0; k < 16; ++k) {
        const int c = j * 16 + k;
        partial += ych[c] * w1[r * NC + c];
    }
#pragma unroll
    for (int m = 8; m > 0; m >>= 1) partial += __shfl_xor(partial, m, 16);
    if (j == 0) hsh[r] = fmaxf(partial + b1[r], 0.f);
    __syncthreads();

    // attn[c] = sigmoid(sum_r h[r]*w2[c,r] + b2[c]); one thread per channel.
    float z = b2[t];
#pragma unroll
    for (int rr = 0; rr < RDIM; ++rr) z += hsh[rr] * w2[t * RDIM + rr];
    const float v = 1.0f / (1.0f + __expf(-z));
    attn[t] = v;
    __syncthreads();

    // rank (strict order, tie -> lower index wins == jax.lax.top_k).
    int rank = 0;
#pragma unroll 4
    for (int c = 0; c < NC; ++c) {
        const float o = attn[c];
        rank += (o > v) || (o == v && c < t);
    }
    const bool s = (rank < KTOP);

    // ballot-based compaction into LDS (ascending channel index).
    const unsigned long long m = __ballot(s);
    if (lane == 0) masks[wid] = m;
    __syncthreads();
    if (s) {
        int pos = __popcll(m & ((lane == 63) ? 0x7FFFFFFFFFFFFFFFull
                                             : ((1ull << lane) - 1ull)));
        for (int w = 0; w < 4; ++w) pos += (w < wid) ? __popcll(masks[w]) : 0;
        sidx[pos] = t;
        saw[pos]  = v;
    }
    __syncthreads();

    // gather + scale: each wave handles one output plane.
    const int k = (blk & 31) * 4 + wid;                 // 0..KTOP-1
    const int c = sidx[k];
    const float w = saw[k];
    const v4f* __restrict__ xin = (const v4f*)(x + ((size_t)b * NC + c) * HW);
    v4f* __restrict__ o = (v4f*)(out + ((size_t)b * KTOP + k) * HW);
#pragma unroll
    for (int i = 0; i < 16; ++i) {
        v4f vv = xin[lane + i * 64];
        v4f rr = vv * w;
        __builtin_nontemporal_store(rr, &o[lane + i * 64]);
    }
}

// ---------------------------------------------------------------------------
extern "C" void kernel_launch(void* const* d_in, const int* in_sizes, int n_in,
                              void* d_out, int out_size, void* d_ws, size_t ws_size,
                              hipStream_t stream) {
    const float* x  = (const float*)d_in[0];
    const float* w1 = (const float*)d_in[1];
    const float* b1 = (const float*)d_in[2];
    const float* w2 = (const float*)d_in[3];
    const float* b2 = (const float*)d_in[4];
    float* out = (float*)d_out;

    float* y = (float*)d_ws;                            // y[NB*NC]

    pool_kernel<<<NB * NC / 4, 256, 0, stream>>>(x, y);
    se_topk_gather_kernel<<<NB * KTOP / 4, 256, 0, stream>>>(
        x, y, w1, b1, w2, b2, out);
}